// Round 2
// baseline (29624.161 us; speedup 1.0000x reference)
//
#include <hip/hip_runtime.h>
#include <math.h>

// ---------------------------------------------------------------------------
// Persistent 2-layer LSTM, fp32. Plain (non-cooperative) launch of 224 blocks
// x 512 threads: 1 block/CU guaranteed by __launch_bounds__(512,2) + 40KB LDS,
// grid < 256 CUs => fully resident; hand-rolled device-scope sense barrier.
// Pipeline per superstep t:  A: layer0 cell s=t | B: layer1 cell s=t-1 |
//                            C: vocab proj s=t-2.   One barrier / superstep.
// ---------------------------------------------------------------------------

constexpr int kV = 256;
constexpr int kH = 1024;
constexpr int kB = 32;
constexpr int kS = 512;
constexpr int G4H = 4096;
constexpr int HB = kH * kB;      // 32768 floats per h buffer

constexpr int NT   = 512;        // threads per block
constexpr int NBLK = 224;
constexpr int NA = 64;           // blocks [0,64):    layer0, 16 units each
constexpr int B0 = 64, NB = 128; // blocks [64,192):  layer1,  8 units each
constexpr int C0 = 192;          // blocks [192,224): proj,    8 vocab each

// ws layout (float offsets); total ~50.4 MB (ws proven >= this in R1)
constexpr int W0T_OFF  = 0;                       // [4][1024][1024] Wh0^T
constexpr int W1XT_OFF = 4 * 1024 * 1024;         // Wx1^T
constexpr int W1HT_OFF = 8 * 1024 * 1024;         // Wh1^T
constexpr int WHYT_OFF = 12 * 1024 * 1024;        // [256][1024] Why^T
constexpr int H0T_OFF  = WHYT_OFF + 256 * 1024;   // [2][1024][32]
constexpr int H1T_OFF  = H0T_OFF + 2 * HB;
constexpr int BAR_OFF  = H1T_OFF + 2 * HB;        // cnt, gen

__device__ __forceinline__ float sigmoidf_(float v) { return 1.f / (1.f + expf(-v)); }

// -------------------------- prep kernels -----------------------------------

__global__ void transpose_w(const float* __restrict__ in, float* __restrict__ out,
                            int rows, int cols) {
  int i = blockIdx.x * blockDim.x + threadIdx.x;
  if (i < rows * cols) {
    int col = i % cols, k = i / cols;
    out[col * rows + k] = in[i];
  }
}

__global__ void zero_state(float* __restrict__ ws) {
  int i = blockIdx.x * blockDim.x + threadIdx.x;
  if (i < 4 * HB + 16) ws[H0T_OFF + i] = 0.f;
}

// -------------------------- grid barrier -----------------------------------

__device__ __forceinline__ void grid_sync(unsigned* cnt, unsigned* gen) {
  __syncthreads();
  if (threadIdx.x == 0) {
    unsigned g = __hip_atomic_load(gen, __ATOMIC_RELAXED, __HIP_MEMORY_SCOPE_AGENT);
    unsigned old = __hip_atomic_fetch_add(cnt, 1u, __ATOMIC_ACQ_REL, __HIP_MEMORY_SCOPE_AGENT);
    if (old == (unsigned)NBLK - 1u) {
      __hip_atomic_store(cnt, 0u, __ATOMIC_RELAXED, __HIP_MEMORY_SCOPE_AGENT);
      __hip_atomic_store(gen, g + 1u, __ATOMIC_RELEASE, __HIP_MEMORY_SCOPE_AGENT);
    } else {
      int guard = 0;
      while (__hip_atomic_load(gen, __ATOMIC_RELAXED, __HIP_MEMORY_SCOPE_AGENT) == g) {
        __builtin_amdgcn_s_sleep(4);
        if (++guard > (1 << 19)) break;  // anti-hang valve; never hit when resident
      }
      (void)__hip_atomic_load(gen, __ATOMIC_ACQUIRE, __HIP_MEMORY_SCOPE_AGENT);
    }
  }
  __syncthreads();
}

// -------------------------- dot-product chunk ------------------------------

#define LOAD4(dst, p, idx) do { float4 t_ = (p)[(idx)]; \
  dst[0] = t_.x; dst[1] = t_.y; dst[2] = t_.z; dst[3] = t_.w; } while (0)

// acc[4][4] += (4 gates x 4 batch x 4 k); 8 float4 loads / 64 FMA
#define GEMM_CHUNK(acc, w0p, w1p, w2p, w3p, h4p, kk) do {                      \
  float wv0[4], wv1[4], wv2[4], wv3[4];                                        \
  LOAD4(wv0, w0p, (kk) >> 2); LOAD4(wv1, w1p, (kk) >> 2);                      \
  LOAD4(wv2, w2p, (kk) >> 2); LOAD4(wv3, w3p, (kk) >> 2);                      \
  float hv0[4], hv1[4], hv2[4], hv3[4];                                        \
  LOAD4(hv0, h4p, ((kk) + 0) * 8 + bg); LOAD4(hv1, h4p, ((kk) + 1) * 8 + bg);  \
  LOAD4(hv2, h4p, ((kk) + 2) * 8 + bg); LOAD4(hv3, h4p, ((kk) + 3) * 8 + bg);  \
  _Pragma("unroll")                                                            \
  for (int i_ = 0; i_ < 4; ++i_) {                                             \
    acc[0][i_] += wv0[0]*hv0[i_] + wv0[1]*hv1[i_] + wv0[2]*hv2[i_] + wv0[3]*hv3[i_]; \
    acc[1][i_] += wv1[0]*hv0[i_] + wv1[1]*hv1[i_] + wv1[2]*hv2[i_] + wv1[3]*hv3[i_]; \
    acc[2][i_] += wv2[0]*hv0[i_] + wv2[1]*hv1[i_] + wv2[2]*hv2[i_] + wv2[3]*hv3[i_]; \
    acc[3][i_] += wv3[0]*hv0[i_] + wv3[1]*hv1[i_] + wv3[2]*hv2[i_] + wv3[3]*hv3[i_]; \
  }                                                                            \
} while (0)

// -------------------------- main persistent kernel -------------------------

extern "C" __global__ void __launch_bounds__(512, 2)
lstm_persist(const int* __restrict__ x,
             const float* __restrict__ Wx0,
             const float* __restrict__ b0v,
             const float* __restrict__ b1v,
             const float* __restrict__ byv,
             float* __restrict__ ws,
             float* __restrict__ out) {
  const float* W0t  = ws + W0T_OFF;
  const float* W1xt = ws + W1XT_OFF;
  const float* W1ht = ws + W1HT_OFF;
  const float* Whyt = ws + WHYT_OFF;
  float* h0t = ws + H0T_OFF;
  float* h1t = ws + H1T_OFF;
  unsigned* bar = (unsigned*)(ws + BAR_OFF);

  const int tid = threadIdx.x;
  const int blk = blockIdx.x;
  const int bg = tid & 7;          // batch quad id (b = bg*4 + i)

  __shared__ float red[8192];      // 32 KB partial sums
  __shared__ float red2[2048];     // 8 KB reduced gates

  float c0r = 0.f;                 // layer0 cell state (A blocks, all threads)
  float c1r = 0.f;                 // layer1 cell state (B blocks, tid<256)

  for (int t = 0; t < kS + 2; ++t) {
    if (blk < NA) {
      // ---------------- A: layer0 cell, s = t --------------------------
      const int s = t;
      if (s < kS) {
        const int ks = (tid >> 3) & 3;   // k-slice of 256
        const int jslot = tid >> 5;      // 0..15
        const int j0 = blk * 16;
        const float* hr = h0t + ((s + 1) & 1) * HB;
        float* hw = h0t + (s & 1) * HB;
        {
          const int j = j0 + jslot;
          float acc[4][4] = {};
          const float4* w0p = (const float4*)(W0t + (0 * kH + j) * kH + ks * 256);
          const float4* w1p = (const float4*)(W0t + (1 * kH + j) * kH + ks * 256);
          const float4* w2p = (const float4*)(W0t + (2 * kH + j) * kH + ks * 256);
          const float4* w3p = (const float4*)(W0t + (3 * kH + j) * kH + ks * 256);
          const float4* h4p = (const float4*)(hr + ks * 256 * kB);
          for (int kk = 0; kk < 256; kk += 4)
            GEMM_CHUNK(acc, w0p, w1p, w2p, w3p, h4p, kk);
          #pragma unroll
          for (int g = 0; g < 4; ++g)
            #pragma unroll
            for (int i2 = 0; i2 < 4; ++i2)
              red[((ks * 16 + jslot) * 4 + g) * 32 + bg * 4 + i2] = acc[g][i2];
        }
        __syncthreads();
        for (int o = tid; o < 2048; o += NT) {
          int b = o & 31, g2 = (o >> 5) & 3, js = o >> 7;
          float sum = 0.f;
          #pragma unroll
          for (int q = 0; q < 4; ++q) sum += red[((q * 16 + js) * 4 + g2) * 32 + b];
          red2[(js * 4 + g2) * 32 + b] = sum;
        }
        __syncthreads();
        {
          const int cu = tid >> 5, cb = tid & 31;
          const int j2 = j0 + cu;
          const int xs = x[cb * kS + s];
          float gi = red2[(cu * 4 + 0) * 32 + cb] + Wx0[xs * G4H + j2]          + b0v[j2];
          float gf = red2[(cu * 4 + 1) * 32 + cb] + Wx0[xs * G4H + kH + j2]     + b0v[kH + j2];
          float gg = red2[(cu * 4 + 2) * 32 + cb] + Wx0[xs * G4H + 2 * kH + j2] + b0v[2 * kH + j2];
          float go = red2[(cu * 4 + 3) * 32 + cb] + Wx0[xs * G4H + 3 * kH + j2] + b0v[3 * kH + j2];
          float cc = sigmoidf_(gf) * c0r + sigmoidf_(gi) * tanhf(gg);
          float hh = sigmoidf_(go) * tanhf(cc);
          c0r = cc;
          hw[j2 * kB + cb] = hh;
        }
      }
    } else if (blk < C0) {
      // ---------------- B: layer1 cell, s = t-1 ------------------------
      const int s = t - 1;
      if (s >= 0 && s < kS) {
        const int ks = (tid >> 3) & 7;   // k-slice of 128
        const int jslot = tid >> 6;      // 0..7
        const int j0 = (blk - B0) * 8;
        const float* h0c = h0t + (s & 1) * HB;        // h0(s)
        const float* h1p = h1t + ((s + 1) & 1) * HB;  // h1(s-1)
        float* hw = h1t + (s & 1) * HB;
        const int j = j0 + jslot;
        float acc[4][4] = {};
        {
          const float4* w0p = (const float4*)(W1xt + (0 * kH + j) * kH + ks * 128);
          const float4* w1p = (const float4*)(W1xt + (1 * kH + j) * kH + ks * 128);
          const float4* w2p = (const float4*)(W1xt + (2 * kH + j) * kH + ks * 128);
          const float4* w3p = (const float4*)(W1xt + (3 * kH + j) * kH + ks * 128);
          const float4* h4p = (const float4*)(h0c + ks * 128 * kB);
          for (int kk = 0; kk < 128; kk += 4)
            GEMM_CHUNK(acc, w0p, w1p, w2p, w3p, h4p, kk);
        }
        {
          const float4* w0p = (const float4*)(W1ht + (0 * kH + j) * kH + ks * 128);
          const float4* w1p = (const float4*)(W1ht + (1 * kH + j) * kH + ks * 128);
          const float4* w2p = (const float4*)(W1ht + (2 * kH + j) * kH + ks * 128);
          const float4* w3p = (const float4*)(W1ht + (3 * kH + j) * kH + ks * 128);
          const float4* h4p = (const float4*)(h1p + ks * 128 * kB);
          for (int kk = 0; kk < 128; kk += 4)
            GEMM_CHUNK(acc, w0p, w1p, w2p, w3p, h4p, kk);
        }
        #pragma unroll
        for (int g = 0; g < 4; ++g)
          #pragma unroll
          for (int i2 = 0; i2 < 4; ++i2)
            red[((ks * 8 + jslot) * 4 + g) * 32 + bg * 4 + i2] = acc[g][i2];
        __syncthreads();
        for (int o = tid; o < 1024; o += NT) {
          int b = o & 31, g2 = (o >> 5) & 3, js = o >> 7;
          float sum = 0.f;
          #pragma unroll
          for (int q = 0; q < 8; ++q) sum += red[((q * 8 + js) * 4 + g2) * 32 + b];
          red2[(js * 4 + g2) * 32 + b] = sum;
        }
        __syncthreads();
        if (tid < 256) {
          const int cu = tid >> 5, cb = tid & 31;
          const int j2 = j0 + cu;
          float gi = red2[(cu * 4 + 0) * 32 + cb] + b1v[j2];
          float gf = red2[(cu * 4 + 1) * 32 + cb] + b1v[kH + j2];
          float gg = red2[(cu * 4 + 2) * 32 + cb] + b1v[2 * kH + j2];
          float go = red2[(cu * 4 + 3) * 32 + cb] + b1v[3 * kH + j2];
          float cc = sigmoidf_(gf) * c1r + sigmoidf_(gi) * tanhf(gg);
          float hh = sigmoidf_(go) * tanhf(cc);
          c1r = cc;
          hw[j2 * kB + cb] = hh;
        }
      }
    } else {
      // ---------------- C: vocab projection, s = t-2 -------------------
      const int s = t - 2;
      if (s >= 0 && s < kS) {
        const int ks = (tid >> 3) & 7;
        const int vslot = tid >> 6;      // 0..7
        const int v0 = (blk - C0) * 8;
        const float* h1c = h1t + (s & 1) * HB;  // h1(s), parity (t-2)&1 == t&1
        const int v = v0 + vslot;
        float acc1[4] = {};
        const float4* w4p = (const float4*)(Whyt + v * kH + ks * 128);
        const float4* h4p = (const float4*)(h1c + ks * 128 * kB);
        for (int kk = 0; kk < 128; kk += 4) {
          float wv[4], hv0[4], hv1[4], hv2[4], hv3[4];
          LOAD4(wv, w4p, kk >> 2);
          LOAD4(hv0, h4p, (kk + 0) * 8 + bg);
          LOAD4(hv1, h4p, (kk + 1) * 8 + bg);
          LOAD4(hv2, h4p, (kk + 2) * 8 + bg);
          LOAD4(hv3, h4p, (kk + 3) * 8 + bg);
          #pragma unroll
          for (int i2 = 0; i2 < 4; ++i2)
            acc1[i2] += wv[0]*hv0[i2] + wv[1]*hv1[i2] + wv[2]*hv2[i2] + wv[3]*hv3[i2];
        }
        #pragma unroll
        for (int i2 = 0; i2 < 4; ++i2)
          red[(ks * 8 + vslot) * 32 + bg * 4 + i2] = acc1[i2];
        __syncthreads();
        if (tid < 256) {
          const int cv = tid & 7, cb = tid >> 3;   // v fastest for store coalescing
          float sum = 0.f;
          #pragma unroll
          for (int q = 0; q < 8; ++q) sum += red[(q * 8 + cv) * 32 + cb];
          out[(s * kB + cb) * kV + v0 + cv] = sum + byv[v0 + cv];
        }
      }
    }
    if (t < kS + 1) grid_sync(&bar[0], &bar[1]);
  }
}

// -------------------------- host launcher ----------------------------------

extern "C" void kernel_launch(void* const* d_in, const int* in_sizes, int n_in,
                              void* d_out, int out_size, void* d_ws, size_t ws_size,
                              hipStream_t stream) {
  const int*   x   = (const int*)d_in[0];
  const float* Wx0 = (const float*)d_in[1];
  const float* Wh0 = (const float*)d_in[2];
  const float* b0v = (const float*)d_in[3];
  const float* Wx1 = (const float*)d_in[4];
  const float* Wh1 = (const float*)d_in[5];
  const float* b1v = (const float*)d_in[6];
  const float* Why = (const float*)d_in[7];
  const float* byv = (const float*)d_in[8];
  float* ws = (float*)d_ws;
  float* outp = (float*)d_out;

  hipLaunchKernelGGL(transpose_w, dim3(16384), dim3(256), 0, stream,
                     Wh0, ws + W0T_OFF, kH, G4H);
  hipLaunchKernelGGL(transpose_w, dim3(16384), dim3(256), 0, stream,
                     Wx1, ws + W1XT_OFF, kH, G4H);
  hipLaunchKernelGGL(transpose_w, dim3(16384), dim3(256), 0, stream,
                     Wh1, ws + W1HT_OFF, kH, G4H);
  hipLaunchKernelGGL(transpose_w, dim3(1024), dim3(256), 0, stream,
                     Why, ws + WHYT_OFF, kH, kV);
  hipLaunchKernelGGL(zero_state, dim3(513), dim3(256), 0, stream, ws);

  hipLaunchKernelGGL(lstm_persist, dim3(NBLK), dim3(NT), 0, stream,
                     x, Wx0, b0v, b1v, byv, ws, outp);
}

// Round 3
// 28642.661 us; speedup vs baseline: 1.0343x; 1.0343x over previous
//
#include <hip/hip_runtime.h>
#include <math.h>

// ---------------------------------------------------------------------------
// Persistent 2-layer LSTM, fp32, 208 blocks x 512 thr (1/CU, fully resident).
// Pipeline: A(64 blks)=layer0 s=t | B(128)=layer1 s=t-1 | C(16)=proj s=t-2.
// Cross-block h traffic via sc0/sc1 (L2-bypass) -> barrier needs NO L2
// invalidate -> weights stay L2-resident across all 514 supersteps.
// h staged to LDS per quarter-K; in-wave shfl_xor reduction over k-slices.
// ---------------------------------------------------------------------------

constexpr int kV = 256, kH = 1024, kB = 32, kS = 512, G4H = 4096;
constexpr int HB = kH * kB;          // 32768 floats per h buffer
constexpr int NT = 512;
constexpr int NBLK = 208;
constexpr int NA = 64;               // blocks [0,64):    layer0, 16 units
constexpr int B0 = 64;               // blocks [64,192):  layer1,  8 units
constexpr int C0 = 192;              // blocks [192,208): proj,   16 vocab

// ws layout (float offsets)
constexpr int W0T_OFF  = 0;                      // Wh0^T  [4][1024][1024]
constexpr int W1XT_OFF = 4 * 1024 * 1024;        // Wx1^T
constexpr int W1HT_OFF = 8 * 1024 * 1024;        // Wh1^T
constexpr int WHYT_OFF = 12 * 1024 * 1024;       // Why^T  [256][1024]
constexpr int H0T_OFF  = WHYT_OFF + 256 * 1024;  // [2][1024][32]
constexpr int H1T_OFF  = H0T_OFF + 2 * HB;
constexpr int BAR_OFF  = H1T_OFF + 2 * HB;       // cnt, gen

// LDS stage geometry: quarter = 256 k x 32 b; [ks(8)][kin(32)][b(32)+pad]
// ks-block = 32*9 + 2 = 290 float4 (8-float pad breaks bank alignment)
constexpr int KSB4 = 290;
constexpr int STAGE4 = 8 * KSB4;     // 2320 float4 = 37 KB

__device__ __forceinline__ float sigmoidf_(float v) { return 1.f / (1.f + expf(-v)); }

// ---------------- coherent (L1/L2-bypass) memory helpers -------------------

__device__ __forceinline__ void coh_store_f32(float* p, float v) {
  asm volatile("global_store_dword %0, %1, off sc0 sc1" :: "v"(p), "v"(v) : "memory");
}
__device__ __forceinline__ unsigned coh_load_u32(const unsigned* p) {
  unsigned v;
  asm volatile("global_load_dword %0, %1, off sc0 sc1\n\ts_waitcnt vmcnt(0)"
               : "=v"(v) : "v"(p) : "memory");
  return v;
}

// stage one quarter (2048 float4) of an h buffer into LDS, 4 f4/thread
__device__ __forceinline__ void stage_q(float4* lds4, const float4* src, int tid) {
  const int id0 = tid, id1 = tid + 512, id2 = tid + 1024, id3 = tid + 1536;
  float4 v0, v1, v2, v3;
  const float4 *p0 = src + id0, *p1 = src + id1, *p2 = src + id2, *p3 = src + id3;
  asm volatile(
      "global_load_dwordx4 %0, %4, off sc0 sc1\n\t"
      "global_load_dwordx4 %1, %5, off sc0 sc1\n\t"
      "global_load_dwordx4 %2, %6, off sc0 sc1\n\t"
      "global_load_dwordx4 %3, %7, off sc0 sc1\n\t"
      "s_waitcnt vmcnt(0)"
      : "=&v"(v0), "=&v"(v1), "=&v"(v2), "=&v"(v3)
      : "v"(p0), "v"(p1), "v"(p2), "v"(p3)
      : "memory");
#define LIDX(id) ((((id) >> 8) & 7) * KSB4 + (((id) >> 3) & 31) * 9 + ((id) & 7))
  lds4[LIDX(id0)] = v0; lds4[LIDX(id1)] = v1; lds4[LIDX(id2)] = v2; lds4[LIDX(id3)] = v3;
#undef LIDX
}

// in-wave reduction over ks (lane bits 3..5)
#define KSRED(v) do { v += __shfl_xor(v, 8, 64); v += __shfl_xor(v, 16, 64); \
                      v += __shfl_xor(v, 32, 64); } while (0)

// -------------------------- prep kernels -----------------------------------

__global__ void transpose_w(const float* __restrict__ in, float* __restrict__ out,
                            int rows, int cols) {
  int i = blockIdx.x * blockDim.x + threadIdx.x;
  if (i < rows * cols) {
    int col = i % cols, k = i / cols;
    out[col * rows + k] = in[i];
  }
}

__global__ void zero_state(float* __restrict__ ws) {
  int i = blockIdx.x * blockDim.x + threadIdx.x;
  if (i < 4 * HB + 16) ws[H0T_OFF + i] = 0.f;
}

// -------------------------- grid barrier (no L2 inv) -----------------------

__device__ __forceinline__ void grid_sync(unsigned* cnt, unsigned* gen) {
  __syncthreads();
  if (threadIdx.x == 0) {
    asm volatile("s_waitcnt vmcnt(0)" ::: "memory");  // h stores done
    unsigned g = coh_load_u32(gen);
    unsigned old = __hip_atomic_fetch_add(cnt, 1u, __ATOMIC_RELAXED,
                                          __HIP_MEMORY_SCOPE_SYSTEM);
    if (old == (unsigned)NBLK - 1u) {
      __hip_atomic_store(cnt, 0u, __ATOMIC_RELAXED, __HIP_MEMORY_SCOPE_SYSTEM);
      asm volatile("s_waitcnt vmcnt(0)" ::: "memory");
      __hip_atomic_store(gen, g + 1u, __ATOMIC_RELAXED, __HIP_MEMORY_SCOPE_SYSTEM);
    } else {
      int guard = 0;
      while (coh_load_u32(gen) == g) {
        __builtin_amdgcn_s_sleep(2);
        if (++guard > (1 << 20)) break;  // anti-hang valve
      }
    }
  }
  __syncthreads();
}

// -------------------------- main persistent kernel -------------------------

extern "C" __global__ void __launch_bounds__(512, 1)
lstm_persist(const int* __restrict__ x,
             const float* __restrict__ Wx0,
             const float* __restrict__ b0v,
             const float* __restrict__ b1v,
             const float* __restrict__ byv,
             float* __restrict__ ws,
             float* __restrict__ out) {
  const float4* W0t4  = (const float4*)(ws + W0T_OFF);
  const float4* W1xt4 = (const float4*)(ws + W1XT_OFF);
  const float4* W1ht4 = (const float4*)(ws + W1HT_OFF);
  const float4* Whyt4 = (const float4*)(ws + WHYT_OFF);
  float* h0t = ws + H0T_OFF;
  float* h1t = ws + H1T_OFF;
  unsigned* bar = (unsigned*)(ws + BAR_OFF);

  const int tid = threadIdx.x;
  const int blk = blockIdx.x;
  const int bg = tid & 7;           // batch quad (b = bg*4 + i)
  const int ks = (tid >> 3) & 7;    // k-slice within quarter (32 k each)
  const int wv = tid >> 6;          // wave 0..7

  __shared__ float4 hstage4[STAGE4];   // 37 KB
  __shared__ float red2[2048];         // 8 KB

  float c0r = 0.f, c1r = 0.f;

  // per-block row bases (float4 index into weight buffers), wave-uniform
  int rowA[8], rowBx[4], rowBh[4], rowC[2];
  if (blk < NA) {
    const int j = blk * 16 + wv * 2;
    #pragma unroll
    for (int du = 0; du < 2; ++du)
      #pragma unroll
      for (int g = 0; g < 4; ++g)
        rowA[du * 4 + g] = (g * kH + j + du) * (kH / 4);
  } else if (blk < C0) {
    const int j = (blk - B0) * 8 + wv;
    #pragma unroll
    for (int g = 0; g < 4; ++g) {
      rowBx[g] = (g * kH + j) * (kH / 4);
      rowBh[g] = (g * kH + j) * (kH / 4);
    }
  } else {
    const int v = (blk - C0) * 16 + wv * 2;
    rowC[0] = v * (kH / 4);
    rowC[1] = (v + 1) * (kH / 4);
  }

  #pragma unroll 1
  for (int t = 0; t < kS + 2; ++t) {
    if (blk < NA) {
      // ---------------- A: layer0 cell, s = t ---------------------------
      const int s = t;
      if (s < kS) {
        const float4* hsrc = (const float4*)(h0t + ((s + 1) & 1) * HB);
        float acc[8][4] = {};
        #pragma unroll 1
        for (int q = 0; q < 4; ++q) {
          stage_q(hstage4, hsrc + q * 2048, tid);
          __syncthreads();
          #pragma unroll
          for (int c = 0; c < 8; ++c) {
            float hreg[4][4];
            #pragma unroll
            for (int qq = 0; qq < 4; ++qq) {
              float4 hv = hstage4[ks * KSB4 + (c * 4 + qq) * 9 + bg];
              hreg[qq][0] = hv.x; hreg[qq][1] = hv.y; hreg[qq][2] = hv.z; hreg[qq][3] = hv.w;
            }
            #pragma unroll
            for (int r = 0; r < 8; ++r) {
              float4 wvv = W0t4[rowA[r] + q * 64 + ks * 8 + c];
              float wr[4] = {wvv.x, wvv.y, wvv.z, wvv.w};
              #pragma unroll
              for (int qq = 0; qq < 4; ++qq)
                #pragma unroll
                for (int i = 0; i < 4; ++i)
                  acc[r][i] += wr[qq] * hreg[qq][i];
            }
          }
          __syncthreads();
        }
        #pragma unroll
        for (int r = 0; r < 8; ++r)
          #pragma unroll
          for (int i = 0; i < 4; ++i) KSRED(acc[r][i]);
        if (ks == 0) {
          float4* red24 = (float4*)red2;
          #pragma unroll
          for (int r = 0; r < 8; ++r)
            red24[(wv * 8 + r) * 8 + bg] = make_float4(acc[r][0], acc[r][1], acc[r][2], acc[r][3]);
        }
        __syncthreads();
        {
          const int ul = tid >> 5, cb = tid & 31;
          const int j2 = blk * 16 + ul;
          const int ru = (ul >> 1) * 8 + (ul & 1) * 4;
          const int xs = x[cb * kS + s];
          float gi = red2[(ru + 0) * 32 + cb] + Wx0[xs * G4H + j2]           + b0v[j2];
          float gf = red2[(ru + 1) * 32 + cb] + Wx0[xs * G4H + kH + j2]      + b0v[kH + j2];
          float gg = red2[(ru + 2) * 32 + cb] + Wx0[xs * G4H + 2 * kH + j2]  + b0v[2 * kH + j2];
          float go = red2[(ru + 3) * 32 + cb] + Wx0[xs * G4H + 3 * kH + j2]  + b0v[3 * kH + j2];
          float cc = sigmoidf_(gf) * c0r + sigmoidf_(gi) * tanhf(gg);
          float hh = sigmoidf_(go) * tanhf(cc);
          c0r = cc;
          coh_store_f32(h0t + (s & 1) * HB + j2 * kB + cb, hh);
        }
        __syncthreads();
      }
    } else if (blk < C0) {
      // ---------------- B: layer1 cell, s = t-1 -------------------------
      const int s = t - 1;
      if (s >= 0 && s < kS) {
        const float4* h0c = (const float4*)(h0t + (s & 1) * HB);
        const float4* h1p = (const float4*)(h1t + ((s + 1) & 1) * HB);
        float acc[2][4][4] = {};
        #pragma unroll 1
        for (int rd = 0; rd < 8; ++rd) {
          const int m = rd >> 2, q = rd & 3;
          stage_q(hstage4, (m ? h1p : h0c) + q * 2048, tid);
          __syncthreads();
          const float4* wb = m ? W1ht4 : W1xt4;
          const int* rb = m ? rowBh : rowBx;
          #pragma unroll
          for (int c = 0; c < 8; ++c) {
            float hreg[4][4];
            #pragma unroll
            for (int qq = 0; qq < 4; ++qq) {
              float4 hv = hstage4[ks * KSB4 + (c * 4 + qq) * 9 + bg];
              hreg[qq][0] = hv.x; hreg[qq][1] = hv.y; hreg[qq][2] = hv.z; hreg[qq][3] = hv.w;
            }
            #pragma unroll
            for (int g = 0; g < 4; ++g) {
              float4 wvv = wb[rb[g] + q * 64 + ks * 8 + c];
              float wr[4] = {wvv.x, wvv.y, wvv.z, wvv.w};
              #pragma unroll
              for (int qq = 0; qq < 4; ++qq)
                #pragma unroll
                for (int i = 0; i < 4; ++i)
                  acc[m][g][i] += wr[qq] * hreg[qq][i];
            }
          }
          __syncthreads();
        }
        #pragma unroll
        for (int g = 0; g < 4; ++g)
          #pragma unroll
          for (int i = 0; i < 4; ++i) {
            float sum = acc[0][g][i] + acc[1][g][i];
            KSRED(sum);
            acc[0][g][i] = sum;
          }
        if (ks == 0) {
          float4* red24 = (float4*)red2;
          #pragma unroll
          for (int g = 0; g < 4; ++g)
            red24[(wv * 4 + g) * 8 + bg] =
                make_float4(acc[0][g][0], acc[0][g][1], acc[0][g][2], acc[0][g][3]);
        }
        __syncthreads();
        if (tid < 256) {
          const int ul = tid >> 5, cb = tid & 31;
          const int j2 = (blk - B0) * 8 + ul;
          float gi = red2[(ul * 4 + 0) * 32 + cb] + b1v[j2];
          float gf = red2[(ul * 4 + 1) * 32 + cb] + b1v[kH + j2];
          float gg = red2[(ul * 4 + 2) * 32 + cb] + b1v[2 * kH + j2];
          float go = red2[(ul * 4 + 3) * 32 + cb] + b1v[3 * kH + j2];
          float cc = sigmoidf_(gf) * c1r + sigmoidf_(gi) * tanhf(gg);
          float hh = sigmoidf_(go) * tanhf(cc);
          c1r = cc;
          coh_store_f32(h1t + (s & 1) * HB + j2 * kB + cb, hh);
        }
        __syncthreads();
      }
    } else {
      // ---------------- C: vocab projection, s = t-2 --------------------
      const int s = t - 2;
      if (s >= 0 && s < kS) {
        const float4* h1c = (const float4*)(h1t + (s & 1) * HB);
        float acc[2][4] = {};
        #pragma unroll 1
        for (int q = 0; q < 4; ++q) {
          stage_q(hstage4, h1c + q * 2048, tid);
          __syncthreads();
          #pragma unroll
          for (int c = 0; c < 8; ++c) {
            float hreg[4][4];
            #pragma unroll
            for (int qq = 0; qq < 4; ++qq) {
              float4 hv = hstage4[ks * KSB4 + (c * 4 + qq) * 9 + bg];
              hreg[qq][0] = hv.x; hreg[qq][1] = hv.y; hreg[qq][2] = hv.z; hreg[qq][3] = hv.w;
            }
            #pragma unroll
            for (int r = 0; r < 2; ++r) {
              float4 wvv = Whyt4[rowC[r] + q * 64 + ks * 8 + c];
              float wr[4] = {wvv.x, wvv.y, wvv.z, wvv.w};
              #pragma unroll
              for (int qq = 0; qq < 4; ++qq)
                #pragma unroll
                for (int i = 0; i < 4; ++i)
                  acc[r][i] += wr[qq] * hreg[qq][i];
            }
          }
          __syncthreads();
        }
        #pragma unroll
        for (int r = 0; r < 2; ++r)
          #pragma unroll
          for (int i = 0; i < 4; ++i) KSRED(acc[r][i]);
        if (ks == 0) {
          float4* red24 = (float4*)red2;
          #pragma unroll
          for (int r = 0; r < 2; ++r)
            red24[(wv * 2 + r) * 8 + bg] = make_float4(acc[r][0], acc[r][1], acc[r][2], acc[r][3]);
        }
        __syncthreads();
        {
          const int cb = tid >> 4, vl = tid & 15;
          const int vg = (blk - C0) * 16 + vl;
          out[(s * kB + cb) * kV + vg] = red2[vl * 32 + cb] + byv[vg];
        }
        __syncthreads();
      }
    }
    if (t < kS + 1) grid_sync(&bar[0], &bar[1]);
  }
}

// -------------------------- host launcher ----------------------------------

extern "C" void kernel_launch(void* const* d_in, const int* in_sizes, int n_in,
                              void* d_out, int out_size, void* d_ws, size_t ws_size,
                              hipStream_t stream) {
  const int*   x   = (const int*)d_in[0];
  const float* Wx0 = (const float*)d_in[1];
  const float* Wh0 = (const float*)d_in[2];
  const float* b0v = (const float*)d_in[3];
  const float* Wx1 = (const float*)d_in[4];
  const float* Wh1 = (const float*)d_in[5];
  const float* b1v = (const float*)d_in[6];
  const float* Why = (const float*)d_in[7];
  const float* byv = (const float*)d_in[8];
  float* ws = (float*)d_ws;
  float* outp = (float*)d_out;

  hipLaunchKernelGGL(transpose_w, dim3(16384), dim3(256), 0, stream,
                     Wh0, ws + W0T_OFF, kH, G4H);
  hipLaunchKernelGGL(transpose_w, dim3(16384), dim3(256), 0, stream,
                     Wx1, ws + W1XT_OFF, kH, G4H);
  hipLaunchKernelGGL(transpose_w, dim3(16384), dim3(256), 0, stream,
                     Wh1, ws + W1HT_OFF, kH, G4H);
  hipLaunchKernelGGL(transpose_w, dim3(1024), dim3(256), 0, stream,
                     Why, ws + WHYT_OFF, kH, kV);
  hipLaunchKernelGGL(zero_state, dim3(513), dim3(256), 0, stream, ws);

  hipLaunchKernelGGL(lstm_persist, dim3(NBLK), dim3(NT), 0, stream,
                     x, Wx0, b0v, b1v, byv, ws, outp);
}

// Round 4
// 25600.061 us; speedup vs baseline: 1.1572x; 1.1189x over previous
//
#include <hip/hip_runtime.h>
#include <math.h>

// ---------------------------------------------------------------------------
// Persistent 2-layer LSTM, fp32, 208 blocks x 512 thr (1/CU, fully resident).
// Pipeline: A(64 blks)=layer0 s=t | B(128)=layer1 s=t-1 | C(16)=proj s=t-2.
// Cross-block h traffic via sc0/sc1 (cache-bypass) loads/stores.
// R4: contention-free flag barrier (parallel per-block flag stores + one
// wave-parallel root poll) replacing 208 serialized atomic RMWs (~52us/step).
// ---------------------------------------------------------------------------

constexpr int kV = 256, kH = 1024, kB = 32, kS = 512, G4H = 4096;
constexpr int HB = kH * kB;          // 32768 floats per h buffer
constexpr int NT = 512;
constexpr int NBLK = 208;
constexpr int NA = 64;               // blocks [0,64):    layer0, 16 units
constexpr int B0 = 64;               // blocks [64,192):  layer1,  8 units
constexpr int C0 = 192;              // blocks [192,208): proj,   16 vocab
constexpr int ROOT = NBLK - 1;       // root = last C block (lightest phase)

// ws layout (float offsets)
constexpr int W0T_OFF  = 0;                      // Wh0^T  [4][1024][1024]
constexpr int W1XT_OFF = 4 * 1024 * 1024;        // Wx1^T
constexpr int W1HT_OFF = 8 * 1024 * 1024;        // Wh1^T
constexpr int WHYT_OFF = 12 * 1024 * 1024;       // Why^T  [256][1024]
constexpr int H0T_OFF  = WHYT_OFF + 256 * 1024;  // [2][1024][32]
constexpr int H1T_OFF  = H0T_OFF + 2 * HB;
constexpr int BAR_OFF  = H1T_OFF + 2 * HB;       // arrive[256*16] u32, gen

// LDS stage geometry: quarter = 256 k x 32 b; [ks(8)][kin(32)][b(32)+pad]
constexpr int KSB4 = 290;
constexpr int STAGE4 = 8 * KSB4;     // 2320 float4 = 37 KB

__device__ __forceinline__ float sigmoidf_(float v) { return 1.f / (1.f + expf(-v)); }

// ---------------- coherent (cache-bypass) memory helpers -------------------

__device__ __forceinline__ void coh_store_u32(unsigned* p, unsigned v) {
  asm volatile("global_store_dword %0, %1, off sc0 sc1" :: "v"(p), "v"(v) : "memory");
}
__device__ __forceinline__ void coh_store_f32(float* p, float v) {
  asm volatile("global_store_dword %0, %1, off sc0 sc1" :: "v"(p), "v"(v) : "memory");
}
__device__ __forceinline__ unsigned coh_load_u32(const unsigned* p) {
  unsigned v;
  asm volatile("global_load_dword %0, %1, off sc0 sc1\n\ts_waitcnt vmcnt(0)"
               : "=v"(v) : "v"(p) : "memory");
  return v;
}
// 4 scattered coherent dword loads, one waitcnt (root poll)
__device__ __forceinline__ void coh_load4_u32(const unsigned* p0, const unsigned* p1,
                                              const unsigned* p2, const unsigned* p3,
                                              unsigned& a, unsigned& b,
                                              unsigned& c, unsigned& d) {
  asm volatile(
      "global_load_dword %0, %4, off sc0 sc1\n\t"
      "global_load_dword %1, %5, off sc0 sc1\n\t"
      "global_load_dword %2, %6, off sc0 sc1\n\t"
      "global_load_dword %3, %7, off sc0 sc1\n\t"
      "s_waitcnt vmcnt(0)"
      : "=&v"(a), "=&v"(b), "=&v"(c), "=&v"(d)
      : "v"(p0), "v"(p1), "v"(p2), "v"(p3) : "memory");
}

// stage one quarter (2048 float4) of an h buffer into LDS, 4 f4/thread
__device__ __forceinline__ void stage_q(float4* lds4, const float4* src, int tid) {
  const int id0 = tid, id1 = tid + 512, id2 = tid + 1024, id3 = tid + 1536;
  float4 v0, v1, v2, v3;
  const float4 *p0 = src + id0, *p1 = src + id1, *p2 = src + id2, *p3 = src + id3;
  asm volatile(
      "global_load_dwordx4 %0, %4, off sc0 sc1\n\t"
      "global_load_dwordx4 %1, %5, off sc0 sc1\n\t"
      "global_load_dwordx4 %2, %6, off sc0 sc1\n\t"
      "global_load_dwordx4 %3, %7, off sc0 sc1\n\t"
      "s_waitcnt vmcnt(0)"
      : "=&v"(v0), "=&v"(v1), "=&v"(v2), "=&v"(v3)
      : "v"(p0), "v"(p1), "v"(p2), "v"(p3)
      : "memory");
#define LIDX(id) ((((id) >> 8) & 7) * KSB4 + (((id) >> 3) & 31) * 9 + ((id) & 7))
  lds4[LIDX(id0)] = v0; lds4[LIDX(id1)] = v1; lds4[LIDX(id2)] = v2; lds4[LIDX(id3)] = v3;
#undef LIDX
}

// in-wave reduction over ks (lane bits 3..5)
#define KSRED(v) do { v += __shfl_xor(v, 8, 64); v += __shfl_xor(v, 16, 64); \
                      v += __shfl_xor(v, 32, 64); } while (0)

// -------------------------- prep kernels -----------------------------------

__global__ void transpose_w(const float* __restrict__ in, float* __restrict__ out,
                            int rows, int cols) {
  int i = blockIdx.x * blockDim.x + threadIdx.x;
  if (i < rows * cols) {
    int col = i % cols, k = i / cols;
    out[col * rows + k] = in[i];
  }
}

__global__ void zero_state(float* __restrict__ ws) {
  int i = blockIdx.x * blockDim.x + threadIdx.x;
  if (i < 4 * HB + 8192) ws[H0T_OFF + i] = 0.f;   // h bufs + barrier flags
}

// -------------------------- main persistent kernel -------------------------

extern "C" __global__ void __launch_bounds__(512, 1)
lstm_persist(const int* __restrict__ x,
             const float* __restrict__ Wx0,
             const float* __restrict__ b0v,
             const float* __restrict__ b1v,
             const float* __restrict__ byv,
             float* __restrict__ ws,
             float* __restrict__ out) {
  const float4* W0t4  = (const float4*)(ws + W0T_OFF);
  const float4* W1xt4 = (const float4*)(ws + W1XT_OFF);
  const float4* W1ht4 = (const float4*)(ws + W1HT_OFF);
  const float4* Whyt4 = (const float4*)(ws + WHYT_OFF);
  float* h0t = ws + H0T_OFF;
  float* h1t = ws + H1T_OFF;
  unsigned* arrive = (unsigned*)(ws + BAR_OFF);   // stride-16 padded flags
  unsigned* gen = arrive + 4096;

  const int tid = threadIdx.x;
  const int blk = blockIdx.x;
  const int bg = tid & 7;           // batch quad (b = bg*4 + i)
  const int ks = (tid >> 3) & 7;    // k-slice within quarter (32 k each)
  const int wv = tid >> 6;          // wave 0..7

  __shared__ float4 hstage4[STAGE4];   // 37 KB
  __shared__ float red2[2048];         // 8 KB

  float c0r = 0.f, c1r = 0.f;

  // per-block row bases (float4 index into weight buffers), wave-uniform
  int rowA[8], rowBx[4], rowBh[4], rowC[2];
  if (blk < NA) {
    const int j = blk * 16 + wv * 2;
    #pragma unroll
    for (int du = 0; du < 2; ++du)
      #pragma unroll
      for (int g = 0; g < 4; ++g)
        rowA[du * 4 + g] = (g * kH + j + du) * (kH / 4);
  } else if (blk < C0) {
    const int j = (blk - B0) * 8 + wv;
    #pragma unroll
    for (int g = 0; g < 4; ++g) {
      rowBx[g] = (g * kH + j) * (kH / 4);
      rowBh[g] = (g * kH + j) * (kH / 4);
    }
  } else {
    const int v = (blk - C0) * 16 + wv * 2;
    rowC[0] = v * (kH / 4);
    rowC[1] = (v + 1) * (kH / 4);
  }

  #pragma unroll 1
  for (int t = 0; t < kS + 2; ++t) {
    if (blk < NA) {
      // ---------------- A: layer0 cell, s = t ---------------------------
      const int s = t;
      if (s < kS) {
        const float4* hsrc = (const float4*)(h0t + ((s + 1) & 1) * HB);
        float acc[8][4] = {};
        #pragma unroll 1
        for (int q = 0; q < 4; ++q) {
          stage_q(hstage4, hsrc + q * 2048, tid);
          __syncthreads();
          #pragma unroll
          for (int c = 0; c < 8; ++c) {
            float hreg[4][4];
            #pragma unroll
            for (int qq = 0; qq < 4; ++qq) {
              float4 hv = hstage4[ks * KSB4 + (c * 4 + qq) * 9 + bg];
              hreg[qq][0] = hv.x; hreg[qq][1] = hv.y; hreg[qq][2] = hv.z; hreg[qq][3] = hv.w;
            }
            #pragma unroll
            for (int r = 0; r < 8; ++r) {
              float4 wvv = W0t4[rowA[r] + q * 64 + ks * 8 + c];
              float wr[4] = {wvv.x, wvv.y, wvv.z, wvv.w};
              #pragma unroll
              for (int qq = 0; qq < 4; ++qq)
                #pragma unroll
                for (int i = 0; i < 4; ++i)
                  acc[r][i] += wr[qq] * hreg[qq][i];
            }
          }
          __syncthreads();
        }
        #pragma unroll
        for (int r = 0; r < 8; ++r)
          #pragma unroll
          for (int i = 0; i < 4; ++i) KSRED(acc[r][i]);
        if (ks == 0) {
          float4* red24 = (float4*)red2;
          #pragma unroll
          for (int r = 0; r < 8; ++r)
            red24[(wv * 8 + r) * 8 + bg] = make_float4(acc[r][0], acc[r][1], acc[r][2], acc[r][3]);
        }
        __syncthreads();
        {
          const int ul = tid >> 5, cb = tid & 31;
          const int j2 = blk * 16 + ul;
          const int ru = (ul >> 1) * 8 + (ul & 1) * 4;
          const int xs = x[cb * kS + s];
          float gi = red2[(ru + 0) * 32 + cb] + Wx0[xs * G4H + j2]           + b0v[j2];
          float gf = red2[(ru + 1) * 32 + cb] + Wx0[xs * G4H + kH + j2]      + b0v[kH + j2];
          float gg = red2[(ru + 2) * 32 + cb] + Wx0[xs * G4H + 2 * kH + j2]  + b0v[2 * kH + j2];
          float go = red2[(ru + 3) * 32 + cb] + Wx0[xs * G4H + 3 * kH + j2]  + b0v[3 * kH + j2];
          float cc = sigmoidf_(gf) * c0r + sigmoidf_(gi) * tanhf(gg);
          float hh = sigmoidf_(go) * tanhf(cc);
          c0r = cc;
          coh_store_f32(h0t + (s & 1) * HB + j2 * kB + cb, hh);
        }
        __syncthreads();
      }
    } else if (blk < C0) {
      // ---------------- B: layer1 cell, s = t-1 -------------------------
      const int s = t - 1;
      if (s >= 0 && s < kS) {
        const float4* h0c = (const float4*)(h0t + (s & 1) * HB);
        const float4* h1p = (const float4*)(h1t + ((s + 1) & 1) * HB);
        float acc[2][4][4] = {};
        #pragma unroll 1
        for (int rd = 0; rd < 8; ++rd) {
          const int m = rd >> 2, q = rd & 3;
          stage_q(hstage4, (m ? h1p : h0c) + q * 2048, tid);
          __syncthreads();
          const float4* wb = m ? W1ht4 : W1xt4;
          const int* rb = m ? rowBh : rowBx;
          #pragma unroll
          for (int c = 0; c < 8; ++c) {
            float hreg[4][4];
            #pragma unroll
            for (int qq = 0; qq < 4; ++qq) {
              float4 hv = hstage4[ks * KSB4 + (c * 4 + qq) * 9 + bg];
              hreg[qq][0] = hv.x; hreg[qq][1] = hv.y; hreg[qq][2] = hv.z; hreg[qq][3] = hv.w;
            }
            #pragma unroll
            for (int g = 0; g < 4; ++g) {
              float4 wvv = wb[rb[g] + q * 64 + ks * 8 + c];
              float wr[4] = {wvv.x, wvv.y, wvv.z, wvv.w};
              #pragma unroll
              for (int qq = 0; qq < 4; ++qq)
                #pragma unroll
                for (int i = 0; i < 4; ++i)
                  acc[m][g][i] += wr[qq] * hreg[qq][i];
            }
          }
          __syncthreads();
        }
        #pragma unroll
        for (int g = 0; g < 4; ++g)
          #pragma unroll
          for (int i = 0; i < 4; ++i) {
            float sum = acc[0][g][i] + acc[1][g][i];
            KSRED(sum);
            acc[0][g][i] = sum;
          }
        if (ks == 0) {
          float4* red24 = (float4*)red2;
          #pragma unroll
          for (int g = 0; g < 4; ++g)
            red24[(wv * 4 + g) * 8 + bg] =
                make_float4(acc[0][g][0], acc[0][g][1], acc[0][g][2], acc[0][g][3]);
        }
        __syncthreads();
        if (tid < 256) {
          const int ul = tid >> 5, cb = tid & 31;
          const int j2 = (blk - B0) * 8 + ul;
          float gi = red2[(ul * 4 + 0) * 32 + cb] + b1v[j2];
          float gf = red2[(ul * 4 + 1) * 32 + cb] + b1v[kH + j2];
          float gg = red2[(ul * 4 + 2) * 32 + cb] + b1v[2 * kH + j2];
          float go = red2[(ul * 4 + 3) * 32 + cb] + b1v[3 * kH + j2];
          float cc = sigmoidf_(gf) * c1r + sigmoidf_(gi) * tanhf(gg);
          float hh = sigmoidf_(go) * tanhf(cc);
          c1r = cc;
          coh_store_f32(h1t + (s & 1) * HB + j2 * kB + cb, hh);
        }
        __syncthreads();
      }
    } else {
      // ---------------- C: vocab projection, s = t-2 --------------------
      const int s = t - 2;
      if (s >= 0 && s < kS) {
        const float4* h1c = (const float4*)(h1t + (s & 1) * HB);
        float acc[2][4] = {};
        #pragma unroll 1
        for (int q = 0; q < 4; ++q) {
          stage_q(hstage4, h1c + q * 2048, tid);
          __syncthreads();
          #pragma unroll
          for (int c = 0; c < 8; ++c) {
            float hreg[4][4];
            #pragma unroll
            for (int qq = 0; qq < 4; ++qq) {
              float4 hv = hstage4[ks * KSB4 + (c * 4 + qq) * 9 + bg];
              hreg[qq][0] = hv.x; hreg[qq][1] = hv.y; hreg[qq][2] = hv.z; hreg[qq][3] = hv.w;
            }
            #pragma unroll
            for (int r = 0; r < 2; ++r) {
              float4 wvv = Whyt4[rowC[r] + q * 64 + ks * 8 + c];
              float wr[4] = {wvv.x, wvv.y, wvv.z, wvv.w};
              #pragma unroll
              for (int qq = 0; qq < 4; ++qq)
                #pragma unroll
                for (int i = 0; i < 4; ++i)
                  acc[r][i] += wr[qq] * hreg[qq][i];
            }
          }
          __syncthreads();
        }
        #pragma unroll
        for (int r = 0; r < 2; ++r)
          #pragma unroll
          for (int i = 0; i < 4; ++i) KSRED(acc[r][i]);
        if (ks == 0) {
          float4* red24 = (float4*)red2;
          #pragma unroll
          for (int r = 0; r < 2; ++r)
            red24[(wv * 2 + r) * 8 + bg] = make_float4(acc[r][0], acc[r][1], acc[r][2], acc[r][3]);
        }
        __syncthreads();
        {
          const int cb = tid >> 4, vl = tid & 15;
          const int vg = (blk - C0) * 16 + vl;
          out[(s * kB + cb) * kV + vg] = red2[vl * 32 + cb] + byv[vg];
        }
        __syncthreads();
      }
    }

    // ---------------- flag barrier (contention-free) --------------------
    if (t < kS + 1) {
      __syncthreads();                         // each wave drains vmcnt here
      const unsigned target = (unsigned)(t + 1);
      if (tid == 0) coh_store_u32(arrive + blk * 16, target);
      if (blk == ROOT) {
        if (tid < 64) {
          const unsigned* q0 = arrive + tid * 16;
          const unsigned* q1 = arrive + (64 + tid) * 16;
          const unsigned* q2 = arrive + (128 + tid) * 16;
          const int i3 = (192 + tid < NBLK) ? (192 + tid) : 0;
          const unsigned* q3 = arrive + i3 * 16;
          int guard = 0;
          for (;;) {
            unsigned a, b, c, d;
            coh_load4_u32(q0, q1, q2, q3, a, b, c, d);
            bool ok = (a >= target) && (b >= target) && (c >= target) && (d >= target);
            if (__all(ok)) break;
            if (++guard > (1 << 18)) break;    // anti-hang valve
          }
          if (tid == 0) coh_store_u32(gen, target);
        }
      } else {
        if (tid == 0) {
          int guard = 0;
          while (coh_load_u32(gen) < target) {
            __builtin_amdgcn_s_sleep(1);
            if (++guard > (1 << 18)) break;    // anti-hang valve
          }
        }
      }
      __syncthreads();
    }
  }
}

// -------------------------- host launcher ----------------------------------

extern "C" void kernel_launch(void* const* d_in, const int* in_sizes, int n_in,
                              void* d_out, int out_size, void* d_ws, size_t ws_size,
                              hipStream_t stream) {
  const int*   x   = (const int*)d_in[0];
  const float* Wx0 = (const float*)d_in[1];
  const float* Wh0 = (const float*)d_in[2];
  const float* b0v = (const float*)d_in[3];
  const float* Wx1 = (const float*)d_in[4];
  const float* Wh1 = (const float*)d_in[5];
  const float* b1v = (const float*)d_in[6];
  const float* Why = (const float*)d_in[7];
  const float* byv = (const float*)d_in[8];
  float* ws = (float*)d_ws;
  float* outp = (float*)d_out;

  hipLaunchKernelGGL(transpose_w, dim3(16384), dim3(256), 0, stream,
                     Wh0, ws + W0T_OFF, kH, G4H);
  hipLaunchKernelGGL(transpose_w, dim3(16384), dim3(256), 0, stream,
                     Wx1, ws + W1XT_OFF, kH, G4H);
  hipLaunchKernelGGL(transpose_w, dim3(16384), dim3(256), 0, stream,
                     Wh1, ws + W1HT_OFF, kH, G4H);
  hipLaunchKernelGGL(transpose_w, dim3(1024), dim3(256), 0, stream,
                     Why, ws + WHYT_OFF, kH, kV);
  hipLaunchKernelGGL(zero_state, dim3(640), dim3(256), 0, stream, ws);

  hipLaunchKernelGGL(lstm_persist, dim3(NBLK), dim3(NT), 0, stream,
                     x, Wx0, b0v, b1v, byv, ws, outp);
}

// Round 6
// 7803.848 us; speedup vs baseline: 3.7961x; 3.2804x over previous
//
#include <hip/hip_runtime.h>
#include <math.h>

// ---------------------------------------------------------------------------
// Persistent 2-layer LSTM via MFMA split-bf16 (hi+lo, 3-term) fp32 emulation.
// 208 blocks x 512 thr (1/CU). Pipeline: A(64)=layer0 s=t | B(128)=layer1
// s=t-1 | C(16)=proj s=t-2. R4 flag barrier. Weights pre-packed to MFMA
// A-fragment order (bf16 hi/lo); h kept [b][k] bf16 hi/lo, staged to LDS per
// 256-k quarter, read as B-fragments (ds_read_b128, stride-33 pad).
// R6 = R5 resubmit (container infra flake): dead vars removed, guards 2^17.
// ---------------------------------------------------------------------------

typedef __attribute__((ext_vector_type(8))) short short8;
typedef __attribute__((ext_vector_type(4))) float f32x4;

constexpr int kV = 256, kH = 1024, kB = 32, kS = 512, G4H = 4096;
constexpr int NT = 512, NBLK = 208;
constexpr int NA = 64, B0 = 64, C0 = 192, ROOT = NBLK - 1;

// ws layout in SHORT units
constexpr long SZW = 4194304L;            // shorts per packed 1024x4096 matrix
constexpr long SZY = 262144L;             // shorts per packed Why array
constexpr long WP0H = 0,        WP0L = SZW;
constexpr long WP1XH = 2*SZW,   WP1XL = 3*SZW;
constexpr long WP1HH = 4*SZW,   WP1HL = 5*SZW;
constexpr long WYH  = 6*SZW,    WYL  = 6*SZW + SZY;
constexpr long HOFF = 6*SZW + 2*SZY;      // h arrays: h0h[2][32K],h0l,h1h,h1l

#define MFMA(a,b,c) __builtin_amdgcn_mfma_f32_16x16x32_bf16(a, b, c, 0, 0, 0)

__device__ __forceinline__ float sigmoidf_(float v) { return 1.f / (1.f + expf(-v)); }

__device__ __forceinline__ void bf16split(float w, unsigned& hi, unsigned& lo) {
  unsigned u = __float_as_uint(w);
  unsigned r = (u + 0x7fffu + ((u >> 16) & 1u)) >> 16;
  float res = w - __uint_as_float(r << 16);
  unsigned u2 = __float_as_uint(res);
  unsigned r2 = (u2 + 0x7fffu + ((u2 >> 16) & 1u)) >> 16;
  hi = r; lo = r2;
}

// ---------------- coherent (cache-bypass) helpers --------------------------

__device__ __forceinline__ void coh_store_u32(unsigned* p, unsigned v) {
  asm volatile("global_store_dword %0, %1, off sc0 sc1" :: "v"(p), "v"(v) : "memory");
}
__device__ __forceinline__ void coh_store_u16(unsigned short* p, unsigned v) {
  asm volatile("global_store_short %0, %1, off sc0 sc1" :: "v"(p), "v"(v) : "memory");
}
__device__ __forceinline__ unsigned coh_load_u32(const unsigned* p) {
  unsigned v;
  asm volatile("global_load_dword %0, %1, off sc0 sc1\n\ts_waitcnt vmcnt(0)"
               : "=v"(v) : "v"(p) : "memory");
  return v;
}
__device__ __forceinline__ void coh4(const void* p0, const void* p1,
                                     const void* p2, const void* p3,
                                     float4& a, float4& b, float4& c, float4& d) {
  asm volatile(
      "global_load_dwordx4 %0, %4, off sc0 sc1\n\t"
      "global_load_dwordx4 %1, %5, off sc0 sc1\n\t"
      "global_load_dwordx4 %2, %6, off sc0 sc1\n\t"
      "global_load_dwordx4 %3, %7, off sc0 sc1\n\t"
      "s_waitcnt vmcnt(0)"
      : "=&v"(a), "=&v"(b), "=&v"(c), "=&v"(d)
      : "v"(p0), "v"(p1), "v"(p2), "v"(p3) : "memory");
}

// stage one 256-k quarter of h (hi+lo) into LDS; all 512 threads
__device__ __forceinline__ void stage_q(short8* HH, short8* HL,
                                        const unsigned short* gH,
                                        const unsigned short* gL,
                                        int qtr, int tid) {
  const int b0_ = tid >> 5, kg = tid & 31, b1_ = b0_ + 16;
  const unsigned short* p0 = gH + b0_ * 1024 + qtr * 256 + kg * 8;
  const unsigned short* p1 = gH + b1_ * 1024 + qtr * 256 + kg * 8;
  const unsigned short* p2 = gL + b0_ * 1024 + qtr * 256 + kg * 8;
  const unsigned short* p3 = gL + b1_ * 1024 + qtr * 256 + kg * 8;
  float4 v0, v1, v2, v3;
  coh4(p0, p1, p2, p3, v0, v1, v2, v3);
  HH[b0_ * 33 + kg] = *(short8*)&v0;
  HH[b1_ * 33 + kg] = *(short8*)&v1;
  HL[b0_ * 33 + kg] = *(short8*)&v2;
  HL[b1_ * 33 + kg] = *(short8*)&v3;
}

// -------------------------- prep kernels -----------------------------------

// in[k][ncols] fp32 -> packed [slab=kk*4+q][row][8] bf16 hi/lo fragments
__global__ void pack_w(const float* __restrict__ in, unsigned short* __restrict__ hi,
                       unsigned short* __restrict__ lo, int ncols) {
  int id = blockIdx.x * 256 + threadIdx.x;
  int slab = id / ncols, row = id % ncols;   // slab < 128
  int k0 = (slab >> 2) * 32 + (slab & 3) * 8;
  long ob = ((long)slab * ncols + row) * 8;
  #pragma unroll
  for (int e = 0; e < 8; ++e) {
    float w = in[(long)(k0 + e) * ncols + row];
    unsigned h_, l_;
    bf16split(w, h_, l_);
    hi[ob + e] = (unsigned short)h_;
    lo[ob + e] = (unsigned short)l_;
  }
}

__global__ void zero_state(unsigned* __restrict__ p, int n) {
  int i = blockIdx.x * 256 + threadIdx.x;
  if (i < n) p[i] = 0u;
}

// -------------------------- main persistent kernel -------------------------

extern "C" __global__ void __launch_bounds__(512, 1)
lstm_persist(const int* __restrict__ x,
             const float* __restrict__ Wx0,
             const float* __restrict__ b0v,
             const float* __restrict__ b1v,
             const float* __restrict__ byv,
             unsigned short* __restrict__ wss,
             float* __restrict__ out) {
  const short8* wp0h  = (const short8*)(wss + WP0H);
  const short8* wp0l  = (const short8*)(wss + WP0L);
  const short8* wp1xh = (const short8*)(wss + WP1XH);
  const short8* wp1xl = (const short8*)(wss + WP1XL);
  const short8* wp1hh = (const short8*)(wss + WP1HH);
  const short8* wp1hl = (const short8*)(wss + WP1HL);
  const short8* wyh   = (const short8*)(wss + WYH);
  const short8* wyl   = (const short8*)(wss + WYL);
  unsigned short* h0h = wss + HOFF;            // [2][32][1024]
  unsigned short* h0l = h0h + 65536;
  unsigned short* h1h = h0h + 131072;
  unsigned short* h1l = h0h + 196608;
  unsigned* arrive = (unsigned*)(h0h + 262144);  // stride-16 flags
  unsigned* gen = arrive + 4096;

  const int tid = threadIdx.x, blk = blockIdx.x;
  const int lane = tid & 63, m = lane & 15, quad = lane >> 4, w = tid >> 6;

  __shared__ short8 HSH[32 * 33];   // 16.5 KB  h hi quarter
  __shared__ short8 HSL[32 * 33];   // 16.5 KB  h lo quarter
  __shared__ float gx[2048];        // 8 KB gate/output exchange

  float c0r = 0.f, c1r = 0.f;

  #pragma unroll 1
  for (int t = 0; t < kS + 2; ++t) {
    if (blk < NA) {
      // ---------------- A: layer0 cell, s = t ---------------------------
      const int s = t;
      if (s < kS) {
        const int g = w >> 1, nt = w & 1, j0A = blk * 16;
        const int bcol = nt * 16 + m;
        const short8* aph = wp0h + quad * 4096 + (g * 1024 + j0A + m);
        const short8* apl = wp0l + quad * 4096 + (g * 1024 + j0A + m);
        const int rpar = (s + 1) & 1;
        const unsigned short* gH = h0h + rpar * 32768;
        const unsigned short* gL = h0l + rpar * 32768;
        f32x4 acc = {0.f, 0.f, 0.f, 0.f};
        #pragma unroll 1
        for (int qtr = 0; qtr < 4; ++qtr) {
          stage_q(HSH, HSL, gH, gL, qtr, tid);
          __syncthreads();
          #pragma unroll
          for (int kl = 0; kl < 8; ++kl) {
            const int kk = qtr * 8 + kl;
            short8 ah = aph[kk * 16384];
            short8 al = apl[kk * 16384];
            short8 bh = HSH[bcol * 33 + kl * 4 + quad];
            short8 bl = HSL[bcol * 33 + kl * 4 + quad];
            acc = MFMA(ah, bh, acc);
            acc = MFMA(ah, bl, acc);
            acc = MFMA(al, bh, acc);
          }
          __syncthreads();
        }
        #pragma unroll
        for (int r = 0; r < 4; ++r)
          gx[(g * 16 + quad * 4 + r) * 32 + bcol] = acc[r];
        __syncthreads();
        {
          const int u = tid >> 5, b = tid & 31;
          const int j2 = j0A + u;
          const int xs = x[b * kS + s];
          float gi = gx[(0 * 16 + u) * 32 + b] + Wx0[(long)xs * G4H + j2]            + b0v[j2];
          float gf = gx[(1 * 16 + u) * 32 + b] + Wx0[(long)xs * G4H + kH + j2]       + b0v[kH + j2];
          float gg = gx[(2 * 16 + u) * 32 + b] + Wx0[(long)xs * G4H + 2 * kH + j2]   + b0v[2 * kH + j2];
          float go = gx[(3 * 16 + u) * 32 + b] + Wx0[(long)xs * G4H + 3 * kH + j2]   + b0v[3 * kH + j2];
          float cc = sigmoidf_(gf) * c0r + sigmoidf_(gi) * tanhf(gg);
          float hh = sigmoidf_(go) * tanhf(cc);
          c0r = cc;
          unsigned h_, l_;
          bf16split(hh, h_, l_);
          const int wpar = s & 1;
          coh_store_u16(h0h + wpar * 32768 + b * 1024 + j2, h_);
          coh_store_u16(h0l + wpar * 32768 + b * 1024 + j2, l_);
        }
      }
    } else if (blk < C0) {
      // ---------------- B: layer1 cell, s = t-1 -------------------------
      const int s = t - 1;
      if (s >= 0 && s < kS) {
        const int kq = w >> 2, mt = (w >> 1) & 1, nt = w & 1;
        const int rowB = mt * 16 + m;
        const int gB = rowB >> 3, uB = rowB & 7;
        const int growB = gB * 1024 + (blk - B0) * 8 + uB;
        const int bcol = nt * 16 + m;
        f32x4 acc = {0.f, 0.f, 0.f, 0.f};
        #pragma unroll 1
        for (int half = 0; half < 2; ++half) {
          const int rpar = half ? ((s + 1) & 1) : (s & 1);
          const unsigned short* gH = (half ? h1h : h0h) + rpar * 32768;
          const unsigned short* gL = (half ? h1l : h0l) + rpar * 32768;
          const short8* aph = (half ? wp1hh : wp1xh) + quad * 4096 + growB;
          const short8* apl = (half ? wp1hl : wp1xl) + quad * 4096 + growB;
          #pragma unroll 1
          for (int qtr = 0; qtr < 4; ++qtr) {
            stage_q(HSH, HSL, gH, gL, qtr, tid);
            __syncthreads();
            #pragma unroll
            for (int k2 = 0; k2 < 4; ++k2) {
              const int kl = kq * 4 + k2;
              const int kk = qtr * 8 + kl;
              short8 ah = aph[kk * 16384];
              short8 al = apl[kk * 16384];
              short8 bh = HSH[bcol * 33 + kl * 4 + quad];
              short8 bl = HSL[bcol * 33 + kl * 4 + quad];
              acc = MFMA(ah, bh, acc);
              acc = MFMA(ah, bl, acc);
              acc = MFMA(al, bh, acc);
            }
            __syncthreads();
          }
        }
        #pragma unroll
        for (int r = 0; r < 4; ++r)
          gx[(kq * 32 + mt * 16 + quad * 4 + r) * 32 + bcol] = acc[r];
        __syncthreads();
        if (tid < 256) {
          const int u = tid >> 5, b = tid & 31;
          const int j2 = (blk - B0) * 8 + u;
          float gt[4];
          #pragma unroll
          for (int g = 0; g < 4; ++g) {
            const int row = g * 8 + u;
            gt[g] = gx[row * 32 + b] + gx[(32 + row) * 32 + b] + b1v[g * kH + j2];
          }
          float cc = sigmoidf_(gt[1]) * c1r + sigmoidf_(gt[0]) * tanhf(gt[2]);
          float hh = sigmoidf_(gt[3]) * tanhf(cc);
          c1r = cc;
          unsigned h_, l_;
          bf16split(hh, h_, l_);
          const int wpar = s & 1;
          coh_store_u16(h1h + wpar * 32768 + b * 1024 + j2, h_);
          coh_store_u16(h1l + wpar * 32768 + b * 1024 + j2, l_);
        }
      }
    } else {
      // ---------------- C: vocab projection, s = t-2 --------------------
      const int s = t - 2;
      if (s >= 0 && s < kS) {
        const int kq = w >> 1, nt = w & 1;
        const int growC = (blk - C0) * 16 + m;
        const int bcol = nt * 16 + m;
        const short8* aph = wyh + quad * 256 + growC;
        const short8* apl = wyl + quad * 256 + growC;
        const int rpar = s & 1;
        const unsigned short* gH = h1h + rpar * 32768;
        const unsigned short* gL = h1l + rpar * 32768;
        f32x4 acc = {0.f, 0.f, 0.f, 0.f};
        #pragma unroll 1
        for (int qtr = 0; qtr < 4; ++qtr) {
          stage_q(HSH, HSL, gH, gL, qtr, tid);
          __syncthreads();
          #pragma unroll
          for (int k2 = 0; k2 < 2; ++k2) {
            const int kl = kq * 2 + k2;
            const int kk = qtr * 8 + kl;
            short8 ah = aph[kk * 1024];
            short8 al = apl[kk * 1024];
            short8 bh = HSH[bcol * 33 + kl * 4 + quad];
            short8 bl = HSL[bcol * 33 + kl * 4 + quad];
            acc = MFMA(ah, bh, acc);
            acc = MFMA(ah, bl, acc);
            acc = MFMA(al, bh, acc);
          }
          __syncthreads();
        }
        #pragma unroll
        for (int r = 0; r < 4; ++r)
          gx[(kq * 16 + quad * 4 + r) * 32 + bcol] = acc[r];
        __syncthreads();
        {
          const int b = tid >> 4, vl = tid & 15;
          const int vg = (blk - C0) * 16 + vl;
          float sum = gx[(0 * 16 + vl) * 32 + b] + gx[(1 * 16 + vl) * 32 + b] +
                      gx[(2 * 16 + vl) * 32 + b] + gx[(3 * 16 + vl) * 32 + b];
          out[(s * kB + b) * kV + vg] = sum + byv[vg];
        }
      }
    }

    // ---------------- flag barrier (contention-free, from R4) ------------
    if (t < kS + 1) {
      __syncthreads();                         // drains vmcnt per wave
      const unsigned target = (unsigned)(t + 1);
      if (tid == 0) coh_store_u32(arrive + blk * 16, target);
      if (blk == ROOT) {
        if (tid < 64) {
          const unsigned* q0 = arrive + tid * 16;
          const unsigned* q1 = arrive + (64 + tid) * 16;
          const unsigned* q2 = arrive + (128 + tid) * 16;
          const int i3 = (192 + tid < NBLK) ? (192 + tid) : 0;
          const unsigned* q3 = arrive + i3 * 16;
          int guard = 0;
          for (;;) {
            unsigned a, b, c, d;
            asm volatile(
                "global_load_dword %0, %4, off sc0 sc1\n\t"
                "global_load_dword %1, %5, off sc0 sc1\n\t"
                "global_load_dword %2, %6, off sc0 sc1\n\t"
                "global_load_dword %3, %7, off sc0 sc1\n\t"
                "s_waitcnt vmcnt(0)"
                : "=&v"(a), "=&v"(b), "=&v"(c), "=&v"(d)
                : "v"(q0), "v"(q1), "v"(q2), "v"(q3) : "memory");
            bool ok = (a >= target) && (b >= target) && (c >= target) && (d >= target);
            if (__all(ok)) break;
            if (++guard > (1 << 17)) break;    // anti-hang valve
          }
          if (tid == 0) coh_store_u32(gen, target);
        }
      } else {
        if (tid == 0) {
          int guard = 0;
          while (coh_load_u32(gen) < target) {
            __builtin_amdgcn_s_sleep(1);
            if (++guard > (1 << 17)) break;    // anti-hang valve
          }
        }
      }
      __syncthreads();
    }
  }
}

// -------------------------- host launcher ----------------------------------

extern "C" void kernel_launch(void* const* d_in, const int* in_sizes, int n_in,
                              void* d_out, int out_size, void* d_ws, size_t ws_size,
                              hipStream_t stream) {
  const int*   x   = (const int*)d_in[0];
  const float* Wx0 = (const float*)d_in[1];
  const float* Wh0 = (const float*)d_in[2];
  const float* b0v = (const float*)d_in[3];
  const float* Wx1 = (const float*)d_in[4];
  const float* Wh1 = (const float*)d_in[5];
  const float* b1v = (const float*)d_in[6];
  const float* Why = (const float*)d_in[7];
  const float* byv = (const float*)d_in[8];
  unsigned short* wss = (unsigned short*)d_ws;
  float* outp = (float*)d_out;

  hipLaunchKernelGGL(pack_w, dim3(2048), dim3(256), 0, stream,
                     Wh0, wss + WP0H, wss + WP0L, G4H);
  hipLaunchKernelGGL(pack_w, dim3(2048), dim3(256), 0, stream,
                     Wx1, wss + WP1XH, wss + WP1XL, G4H);
  hipLaunchKernelGGL(pack_w, dim3(2048), dim3(256), 0, stream,
                     Wh1, wss + WP1HH, wss + WP1HL, G4H);
  hipLaunchKernelGGL(pack_w, dim3(128), dim3(256), 0, stream,
                     Why, wss + WYH, wss + WYL, kV);
  // zero h arrays (262144 shorts = 131072 u32) + flags/gen (4097 u32)
  hipLaunchKernelGGL(zero_state, dim3(529), dim3(256), 0, stream,
                     (unsigned*)(wss + HOFF), 131072 + 4100);

  hipLaunchKernelGGL(lstm_persist, dim3(NBLK), dim3(NT), 0, stream,
                     x, Wx0, b0v, b1v, byv, wss, outp);
}